// Round 8
// baseline (744.022 us; speedup 1.0000x reference)
//
#include <hip/hip_runtime.h>

// Problem constants (N=1)
constexpr int W_ = 160;   // input W (x), output dim 1
constexpr int H_ = 192;   // input H (y), output dim 2
constexpr int D_ = 64;    // input D (z), output dim 4 (innermost)
constexpr int C_ = 32;
constexpr int HW_  = H_ * W_;          // 30720
constexpr int DHWi = D_ * HW_;         // 1966080
constexpr int CD   = C_ * D_;          // 2048

// R7 result: x-pair batch + value-pin engaged (353 us, -20%) but VGPR=40 shows
// only ONE batch in flight: per iteration the wave still waits a full ~500cy
// round trip after issuing. R8: SOFTWARE PIPELINE across hh -- two named
// register stages (SA/SB, fully-unrolled loop so all indexing is compile-time,
// rule #20); each iteration computes+issues the NEXT batch before pinning and
// consuming the CURRENT one. The waitcnt pass then emits a COUNTED vmcnt
// (~16) at the pin: current batch drained, next batch stays in flight across
// blend+store+next-address-VALU (T3/T4 counted-vmcnt principle, gather form).
// Keep frozen: L2 phase schedule (FETCH 618->100 MB proven), x-pair dwordx2
// gathers, direct f4 NT stores, zero barriers, 36KB throttle -> 4 blocks/CU.
constexpr int TW = 32, TH = 12, TD = 16;
constexpr int NWT = W_ / TW;             // 5
constexpr int NHT = H_ / TH;             // 16
constexpr int NDT = D_ / TD;             // 4
constexpr int QPP = NWT * NHT;           // 80 blocks per phase
constexpr int CPX = C_ / 8;              // 4 channels per XCD
constexpr int NPH = CPX * NDT;           // 16 phases per XCD
constexpr int LDS_BYTES = 36864;         // 36 KB -> exactly 4 blocks/CU (residency throttle)

typedef float f4_t __attribute__((ext_vector_type(4)));
typedef float f2_t __attribute__((ext_vector_type(2)));

struct Stage {
    unsigned off[4][4];
    float wA[4], wB[4], v0[4], v1[4], s0[4], s1[4];
    f2_t P[4][4];
};

__global__ void __launch_bounds__(256, 4)
affine_grid_sample_kernel(const float* __restrict__ inp,
                          const float* __restrict__ th,
                          float* __restrict__ out)
{
    extern __shared__ float smem[];      // residency throttle only (never touched)

    const int t   = threadIdx.x;
    const int bid = blockIdx.x;
    const int xcd = bid & 7;             // XCD id (dispatch round-robin)
    int r = bid >> 3;                    // 0..1279 within XCD, dispatch order
    const int phase = r / QPP;           // 0..15 slowest: one (c,dt) slab at a time
    const int q     = r - phase * QPP;
    const int c  = xcd * CPX + (phase >> 2);
    const int dt = phase & 3;            // dt fastest -> consecutive phases share z-halo
    const int hs = q / NWT;
    const int wt = q - hs * NWT;
    const int w0 = wt * TW, h0 = hs * TH, d0 = dt * TD;

    if (bid < 0) smem[t] = 0.0f;         // keep dynamic-LDS alloc live (never executes)

    const float th0=th[0], th1=th[1], th2 =th[2],  th3 =th[3];
    const float th4=th[4], th5=th[5], th6 =th[6],  th7 =th[7];
    const float th8=th[8], th9=th[9], th10=th[10], th11=th[11];

    const float* __restrict__ pc = inp + (size_t)c * DHWi;

    // lane map: wave = (wl:16) x (dq:4) -> full 64B store segments per wave.
    const int wl = t & 15;               // w within 16-group
    const int dq = (t >> 4) & 3;         // d-quad: owns d0+4dq .. d0+4dq+3
    const int wh = (t >> 6) & 1;         // w-half of the 32-wide tile
    const int hp = t >> 7;               // h parity (threads 128..255 take odd hh)
    const int w  = w0 + wh * 16 + wl;
    const float xx = fmaf((float)w, 2.0f / (W_ - 1), -1.0f);

    // per-thread z-constants for its 4 d's
    float kzx[4], kzy[4], kzz[4];
    #pragma unroll
    for (int k = 0; k < 4; ++k) {
        const int d = d0 + 4 * dq + k;
        const float zz = fmaf((float)d, 2.0f / (D_ - 1), -1.0f);
        kzx[k] = fmaf(th2,  zz, th3);
        kzy[k] = fmaf(th6,  zz, th7);
        kzz[k] = fmaf(th10, zz, th11);
    }

    float* const ob = out + ((size_t)w * H_ + h0) * CD + (size_t)c * D_ + d0 + 4 * dq;

    // ---- stage helpers (all loops unrolled -> constant indices -> SROA) ----
    auto compute_stage = [&](Stage& S, int hh) {
        const float yy = fmaf((float)(h0 + hh), 2.0f / (H_ - 1), -1.0f);
        #pragma unroll
        for (int k = 0; k < 4; ++k) {
            const float px = (fmaf(th0, xx, fmaf(th1, yy, kzx[k])) + 1.0f) * (0.5f * (W_ - 1));
            const float py = (fmaf(th4, xx, fmaf(th5, yy, kzy[k])) + 1.0f) * (0.5f * (H_ - 1));
            const float pz = (fmaf(th8, xx, fmaf(th9, yy, kzz[k])) + 1.0f) * (0.5f * (D_ - 1));
            const float fx = floorf(px), fy = floorf(py), fz = floorf(pz);
            const int ix0 = (int)fx, iy0 = (int)fy, iz0 = (int)fz;
            const float wx = px - fx, wy = py - fy, wz = pz - fz;
            // zeros-padding: per-axis weight of any OOB corner is zeroed
            const float u0r = ((unsigned)ix0       < (unsigned)W_) ? (1.0f - wx) : 0.0f;
            const float u1r = ((unsigned)(ix0 + 1) < (unsigned)W_) ? wx          : 0.0f;
            S.v0[k] = ((unsigned)iy0       < (unsigned)H_) ? (1.0f - wy) : 0.0f;
            S.v1[k] = ((unsigned)(iy0 + 1) < (unsigned)H_) ? wy          : 0.0f;
            S.s0[k] = ((unsigned)iz0       < (unsigned)D_) ? (1.0f - wz) : 0.0f;
            S.s1[k] = ((unsigned)(iz0 + 1) < (unsigned)D_) ? wz          : 0.0f;
            // pair P = (v[e], v[e+1]) with e = clamp(ix0, 0, W-2). Exact cases:
            //   ix0 in [0,W-2] : (wA,wB) = (u0r,u1r)           P=(x0,x1)
            //   ix0 == -1     : (u1r, 0)  -- x1 is v[0] = P.a
            //   ix0 == W-1    : (0, u0r)  -- x0 is v[W-1] = P.b
            //   else          : u0r=u1r=0 already
            float a = u0r, b = u1r;
            if (ix0 == -1)     { a = u1r; b = 0.0f; }
            if (ix0 == W_ - 1) { a = 0.0f; b = u0r; }
            S.wA[k] = a; S.wB[k] = b;
            const int e = min(max(ix0, 0), W_ - 2);
            const int cy0 = min(max(iy0,     0), H_ - 1);
            const int cy1 = min(max(iy0 + 1, 0), H_ - 1);
            const int cz0 = min(max(iz0,     0), D_ - 1);
            const int cz1 = min(max(iz0 + 1, 0), D_ - 1);
            S.off[k][0] = (unsigned)(cz0 * HW_ + cy0 * W_ + e);
            S.off[k][1] = (unsigned)(cz0 * HW_ + cy1 * W_ + e);
            S.off[k][2] = (unsigned)(cz1 * HW_ + cy0 * W_ + e);
            S.off[k][3] = (unsigned)(cz1 * HW_ + cy1 * W_ + e);
        }
    };

    auto issue_stage = [&](Stage& S) {
        #pragma unroll
        for (int k = 0; k < 4; ++k)
            #pragma unroll
            for (int j = 0; j < 4; ++j)
                __builtin_memcpy(&S.P[k][j], pc + S.off[k][j], 8);  // dwordx2, 4B-aligned
    };

    // Pin ALL 16 results live at one point (value-level pin -- not defeatable
    // by noalias AA): forces back-to-back issue + a single COUNTED vmcnt wait
    // at the consumer while the NEXT stage's loads stay in flight.
    auto pin_stage = [&](Stage& S) {
        asm volatile("" ::
            "v"(S.P[0][0]), "v"(S.P[0][1]), "v"(S.P[0][2]), "v"(S.P[0][3]),
            "v"(S.P[1][0]), "v"(S.P[1][1]), "v"(S.P[1][2]), "v"(S.P[1][3]),
            "v"(S.P[2][0]), "v"(S.P[2][1]), "v"(S.P[2][2]), "v"(S.P[2][3]),
            "v"(S.P[3][0]), "v"(S.P[3][1]), "v"(S.P[3][2]), "v"(S.P[3][3]));
        __builtin_amdgcn_sched_barrier(0);
    };

    auto consume_stage = [&](Stage& S, int hh) {
        f4_t val;
        #pragma unroll
        for (int k = 0; k < 4; ++k) {
            const float x00 = S.wA[k] * S.P[k][0][0] + S.wB[k] * S.P[k][0][1];
            const float x01 = S.wA[k] * S.P[k][1][0] + S.wB[k] * S.P[k][1][1];
            const float x10 = S.wA[k] * S.P[k][2][0] + S.wB[k] * S.P[k][2][1];
            const float x11 = S.wA[k] * S.P[k][3][0] + S.wB[k] * S.P[k][3][1];
            const float e0 = S.v0[k] * x00 + S.v1[k] * x01;
            const float e1 = S.v0[k] * x10 + S.v1[k] * x11;
            val[k] = S.s0[k] * e0 + S.s1[k] * e1;
        }
        // output is write-once streaming: non-temporal
        __builtin_nontemporal_store(val, (f4_t*)(ob + (size_t)hh * CD));
    };

    // ---- software pipeline over the 6 hh iterations (hh = hp + 2*j) ----
    Stage SA, SB;
    compute_stage(SA, hp);
    issue_stage(SA);
    #pragma unroll
    for (int j = 0; j < 6; ++j) {
        Stage& cur = (j & 1) ? SB : SA;   // compile-time after full unroll
        Stage& nxt = (j & 1) ? SA : SB;
        if (j < 5) {
            compute_stage(nxt, hp + 2 * (j + 1));
            issue_stage(nxt);             // next batch in flight across this consume
        }
        pin_stage(cur);                   // counted vmcnt: drain cur only
        consume_stage(cur, hp + 2 * j);
    }
}

extern "C" void kernel_launch(void* const* d_in, const int* in_sizes, int n_in,
                              void* d_out, int out_size, void* d_ws, size_t ws_size,
                              hipStream_t stream)
{
    const float* inp = (const float*)d_in[0];   // [1,32,64,192,160] fp32
    const float* th  = (const float*)d_in[1];   // 12 fp32
    float* out = (float*)d_out;                 // [1,160,192,32,64] fp32

    hipLaunchKernelGGL(affine_grid_sample_kernel, dim3(8 * NPH * QPP), dim3(256),
                       LDS_BYTES, stream, inp, th, out);
}

// Round 9
// 637.805 us; speedup vs baseline: 1.1665x; 1.1665x over previous
//
#include <hip/hip_runtime.h>

// Problem constants (N=1)
constexpr int W_ = 160;   // input W (x), output dim 1
constexpr int H_ = 192;   // input H (y), output dim 2
constexpr int D_ = 64;    // input D (z), output dim 4 (innermost)
constexpr int C_ = 32;
constexpr int HW_  = H_ * W_;          // 30720
constexpr int DHWi = D_ * HW_;         // 1966080
constexpr int CD   = C_ * D_;          // 2048

// R8 post-mortem: two 72-dword Stage structs blew the 128-VGPR cap -> scratch
// spill (WRITE 246->543 MB, FETCH 100->294 MB = pure spill traffic); pipeline
// never ran in registers. R9: stage = ONLY the in-flight load results
// (f2_t P[4][4] = 32 VGPR/stage). Offsets are computed-and-consumed at issue;
// weights are RECOMPUTED at consume (identical expression trees -> bit-identical
// values; ~110 extra VALU ops/iter, free at 33% VALUBusy, and that recompute
// overlaps the in-flight loads). sched_barrier(0) after each issue stops the
// scheduler sinking next-stage loads below the pin (which would degrade the
// counted vmcnt to a full drain).
// Keep frozen: L2 phase schedule (FETCH 618->100 MB proven), x-pair dwordx2
// gathers, value-pin + counted vmcnt, f4 NT stores, no barriers, 36KB throttle.
constexpr int TW = 32, TH = 12, TD = 16;
constexpr int NWT = W_ / TW;             // 5
constexpr int NHT = H_ / TH;             // 16
constexpr int NDT = D_ / TD;             // 4
constexpr int QPP = NWT * NHT;           // 80 blocks per phase
constexpr int CPX = C_ / 8;              // 4 channels per XCD
constexpr int NPH = CPX * NDT;           // 16 phases per XCD
constexpr int LDS_BYTES = 36864;         // 36 KB -> exactly 4 blocks/CU (residency throttle)

typedef float f4_t __attribute__((ext_vector_type(4)));
typedef float f2_t __attribute__((ext_vector_type(2)));

__global__ void __launch_bounds__(256, 4)
affine_grid_sample_kernel(const float* __restrict__ inp,
                          const float* __restrict__ th,
                          float* __restrict__ out)
{
    extern __shared__ float smem[];      // residency throttle only (never touched)

    const int t   = threadIdx.x;
    const int bid = blockIdx.x;
    const int xcd = bid & 7;             // XCD id (dispatch round-robin)
    int r = bid >> 3;                    // 0..1279 within XCD, dispatch order
    const int phase = r / QPP;           // 0..15 slowest: one (c,dt) slab at a time
    const int q     = r - phase * QPP;
    const int c  = xcd * CPX + (phase >> 2);
    const int dt = phase & 3;            // dt fastest -> consecutive phases share z-halo
    const int hs = q / NWT;
    const int wt = q - hs * NWT;
    const int w0 = wt * TW, h0 = hs * TH, d0 = dt * TD;

    if (bid < 0) smem[t] = 0.0f;         // keep dynamic-LDS alloc live (never executes)

    const float th0=th[0], th1=th[1], th2 =th[2],  th3 =th[3];
    const float th4=th[4], th5=th[5], th6 =th[6],  th7 =th[7];
    const float th8=th[8], th9=th[9], th10=th[10], th11=th[11];

    const float* __restrict__ pc = inp + (size_t)c * DHWi;

    // lane map: wave = (wl:16) x (dq:4) -> full 64B store segments per wave.
    const int wl = t & 15;               // w within 16-group
    const int dq = (t >> 4) & 3;         // d-quad: owns d0+4dq .. d0+4dq+3
    const int wh = (t >> 6) & 1;         // w-half of the 32-wide tile
    const int hp = t >> 7;               // h parity (threads 128..255 take odd hh)
    const int w  = w0 + wh * 16 + wl;
    const float xx = fmaf((float)w, 2.0f / (W_ - 1), -1.0f);

    // per-thread z-constants for its 4 d's
    float kzx[4], kzy[4], kzz[4];
    #pragma unroll
    for (int k = 0; k < 4; ++k) {
        const int d = d0 + 4 * dq + k;
        const float zz = fmaf((float)d, 2.0f / (D_ - 1), -1.0f);
        kzx[k] = fmaf(th2,  zz, th3);
        kzy[k] = fmaf(th6,  zz, th7);
        kzz[k] = fmaf(th10, zz, th11);
    }

    float* const ob = out + ((size_t)w * H_ + h0) * CD + (size_t)c * D_ + d0 + 4 * dq;

    // ---- issue: compute offsets (consumed immediately), fire 16 pair-loads ----
    auto issue = [&](f2_t (&P)[4][4], int hh) {
        const float yy = fmaf((float)(h0 + hh), 2.0f / (H_ - 1), -1.0f);
        #pragma unroll
        for (int k = 0; k < 4; ++k) {
            const float px = (fmaf(th0, xx, fmaf(th1, yy, kzx[k])) + 1.0f) * (0.5f * (W_ - 1));
            const float py = (fmaf(th4, xx, fmaf(th5, yy, kzy[k])) + 1.0f) * (0.5f * (H_ - 1));
            const float pz = (fmaf(th8, xx, fmaf(th9, yy, kzz[k])) + 1.0f) * (0.5f * (D_ - 1));
            const int ix0 = (int)floorf(px);
            const int iy0 = (int)floorf(py);
            const int iz0 = (int)floorf(pz);
            const int e   = min(max(ix0,     0), W_ - 2);   // x-pair base
            const int cy0 = min(max(iy0,     0), H_ - 1);
            const int cy1 = min(max(iy0 + 1, 0), H_ - 1);
            const int cz0 = min(max(iz0,     0), D_ - 1);
            const int cz1 = min(max(iz0 + 1, 0), D_ - 1);
            const unsigned o0 = (unsigned)(cz0 * HW_ + cy0 * W_ + e);
            const unsigned o1 = (unsigned)(cz0 * HW_ + cy1 * W_ + e);
            const unsigned o2 = (unsigned)(cz1 * HW_ + cy0 * W_ + e);
            const unsigned o3 = (unsigned)(cz1 * HW_ + cy1 * W_ + e);
            __builtin_memcpy(&P[k][0], pc + o0, 8);   // dwordx2, 4B-aligned
            __builtin_memcpy(&P[k][1], pc + o1, 8);
            __builtin_memcpy(&P[k][2], pc + o2, 8);
            __builtin_memcpy(&P[k][3], pc + o3, 8);
        }
        // loads must not sink below the consumer's pin (would turn the counted
        // vmcnt into a full drain)
        __builtin_amdgcn_sched_barrier(0);
    };

    // ---- consume: recompute weights (overlaps in-flight loads), pin, blend ----
    auto consume = [&](f2_t (&P)[4][4], int hh) {
        const float yy = fmaf((float)(h0 + hh), 2.0f / (H_ - 1), -1.0f);
        float wA[4], wB[4], v0a[4], v1a[4], s0a[4], s1a[4];
        #pragma unroll
        for (int k = 0; k < 4; ++k) {
            // identical expression trees as issue() -> bit-identical px/py/pz
            const float px = (fmaf(th0, xx, fmaf(th1, yy, kzx[k])) + 1.0f) * (0.5f * (W_ - 1));
            const float py = (fmaf(th4, xx, fmaf(th5, yy, kzy[k])) + 1.0f) * (0.5f * (H_ - 1));
            const float pz = (fmaf(th8, xx, fmaf(th9, yy, kzz[k])) + 1.0f) * (0.5f * (D_ - 1));
            const float fx = floorf(px), fy = floorf(py), fz = floorf(pz);
            const int ix0 = (int)fx, iy0 = (int)fy, iz0 = (int)fz;
            const float wx = px - fx, wy = py - fy, wz = pz - fz;
            // zeros-padding: per-axis weight of any OOB corner is zeroed
            const float u0r = ((unsigned)ix0       < (unsigned)W_) ? (1.0f - wx) : 0.0f;
            const float u1r = ((unsigned)(ix0 + 1) < (unsigned)W_) ? wx          : 0.0f;
            v0a[k] = ((unsigned)iy0       < (unsigned)H_) ? (1.0f - wy) : 0.0f;
            v1a[k] = ((unsigned)(iy0 + 1) < (unsigned)H_) ? wy          : 0.0f;
            s0a[k] = ((unsigned)iz0       < (unsigned)D_) ? (1.0f - wz) : 0.0f;
            s1a[k] = ((unsigned)(iz0 + 1) < (unsigned)D_) ? wz          : 0.0f;
            // pair weights on base e=clamp(ix0,0,W-2):
            //   ix0 in [0,W-2]: (u0r,u1r); ix0==-1: (u1r,0); ix0==W-1: (0,u0r)
            float a = u0r, b = u1r;
            if (ix0 == -1)     { a = u1r; b = 0.0f; }
            if (ix0 == W_ - 1) { a = 0.0f; b = u0r; }
            wA[k] = a; wB[k] = b;
        }
        // Pin ALL 16 results live at one point (value-level pin, noalias-proof):
        // waitcnt pass emits a COUNTED vmcnt here -- cur batch drained, next
        // batch (issued after) stays in flight.
        asm volatile("" ::
            "v"(P[0][0]), "v"(P[0][1]), "v"(P[0][2]), "v"(P[0][3]),
            "v"(P[1][0]), "v"(P[1][1]), "v"(P[1][2]), "v"(P[1][3]),
            "v"(P[2][0]), "v"(P[2][1]), "v"(P[2][2]), "v"(P[2][3]),
            "v"(P[3][0]), "v"(P[3][1]), "v"(P[3][2]), "v"(P[3][3]));
        __builtin_amdgcn_sched_barrier(0);

        f4_t val;
        #pragma unroll
        for (int k = 0; k < 4; ++k) {
            const float x00 = wA[k] * P[k][0][0] + wB[k] * P[k][0][1];
            const float x01 = wA[k] * P[k][1][0] + wB[k] * P[k][1][1];
            const float x10 = wA[k] * P[k][2][0] + wB[k] * P[k][2][1];
            const float x11 = wA[k] * P[k][3][0] + wB[k] * P[k][3][1];
            const float e0 = v0a[k] * x00 + v1a[k] * x01;
            const float e1 = v0a[k] * x10 + v1a[k] * x11;
            val[k] = s0a[k] * e0 + s1a[k] * e1;
        }
        // output is write-once streaming: non-temporal
        __builtin_nontemporal_store(val, (f4_t*)(ob + (size_t)hh * CD));
    };

    // ---- software pipeline over the 6 hh iterations (hh = hp + 2*j) ----
    f2_t PA[4][4], PB[4][4];
    issue(PA, hp);
    #pragma unroll
    for (int j = 0; j < 6; ++j) {
        if (j < 5) {
            if (j & 1) issue(PA, hp + 2 * (j + 1));
            else       issue(PB, hp + 2 * (j + 1));
        }
        if (j & 1) consume(PB, hp + 2 * j);
        else       consume(PA, hp + 2 * j);
    }
}

extern "C" void kernel_launch(void* const* d_in, const int* in_sizes, int n_in,
                              void* d_out, int out_size, void* d_ws, size_t ws_size,
                              hipStream_t stream)
{
    const float* inp = (const float*)d_in[0];   // [1,32,64,192,160] fp32
    const float* th  = (const float*)d_in[1];   // 12 fp32
    float* out = (float*)d_out;                 // [1,160,192,32,64] fp32

    hipLaunchKernelGGL(affine_grid_sample_kernel, dim3(8 * NPH * QPP), dim3(256),
                       LDS_BYTES, stream, inp, th, out);
}